// Round 19
// baseline (264.563 us; speedup 1.0000x reference)
//
#include <hip/hip_runtime.h>

#define N_PROT 8192
#define E_PP   163840
#define E_LP   81920
#define NB0    (E_PP / 64)   // 2560 pp blocks (64 edges each)
#define NB1    (E_LP / 64)   // 1280 lp blocks
#define XSTR   132           // padded fp32 row stride in node scratch

typedef float        f32x2  __attribute__((ext_vector_type(2)));
typedef float        f32x4  __attribute__((ext_vector_type(4)));
typedef float        f32x16 __attribute__((ext_vector_type(16)));
typedef unsigned int u32x2  __attribute__((ext_vector_type(2)));
typedef unsigned int u32x4  __attribute__((ext_vector_type(4)));
typedef short        s16x8  __attribute__((ext_vector_type(8)));
typedef unsigned short ushort_t;

union frag32 { u32x4 v; s16x8 s; };

__device__ inline unsigned short f2bf(float f) {
  unsigned int u = __float_as_uint(f);
  u = u + 0x7FFFu + ((u >> 16) & 1u);   // RTNE
  return (unsigned short)(u >> 16);
}

__device__ inline unsigned int cvt_pk_bf16(float lo, float hi) {
  unsigned int r;
  asm("v_cvt_pk_bf16_f32 %0, %1, %2" : "=v"(r) : "v"(lo), "v"(hi));
  return r;
}

__device__ inline float bf_lo(unsigned int u) { return __uint_as_float(u << 16); }
__device__ inline float bf_hi(unsigned int u) { return __uint_as_float(u & 0xffff0000u); }

__device__ inline float gelu_tanh(float x) {
  const float c0 = 0.7978845608028654f;
  float inner = c0 * (x + 0.044715f * x * x * x);
  return 0.5f * x * (1.0f + tanhf(inner));
}

// ---------------------------------------------------------------------------
// prep_all (validated R14)
// ---------------------------------------------------------------------------
__global__ void prep_all(const float* __restrict__ Watt0, const float* __restrict__ Wval0,
                         const float* __restrict__ Watt1, const float* __restrict__ Wval1,
                         const float* __restrict__ Wh1, const float* __restrict__ Wh2,
                         const float* __restrict__ Wm1, const float* __restrict__ Wm2,
                         const float* __restrict__ batt0, const float* __restrict__ a0,
                         const float* __restrict__ bval0,
                         const float* __restrict__ batt1, const float* __restrict__ a1,
                         const float* __restrict__ bval1,
                         ushort_t* __restrict__ Bt0, ushort_t* __restrict__ Bt1,
                         ushort_t* __restrict__ Wh1t, ushort_t* __restrict__ Wh2t,
                         ushort_t* __restrict__ Wm1t, ushort_t* __restrict__ Wm2t,
                         float* __restrict__ P, int* __restrict__ zbuf)
{
  int b = blockIdx.x;
  const int t = threadIdx.x;
  if (b < 576) {
    const int i = b * 256 + t;
    const int k = i >> 8, n = i & 255;
    const float v = (n < 128) ? Watt0[(size_t)k * 128 + n] : Wval0[(size_t)k * 128 + (n - 128)];
    Bt0[(size_t)(k >> 3) * 2048 + n * 8 + (k & 7)] = f2bf(v);
    return;
  }
  b -= 576;
  if (b < 384) {
    const int i = b * 256 + t;
    const int k = i >> 8, n = i & 255;
    const float v = (n < 128) ? Watt1[(size_t)k * 128 + n] : Wval1[(size_t)k * 128 + (n - 128)];
    Bt1[(size_t)(k >> 3) * 2048 + n * 8 + (k & 7)] = f2bf(v);
    return;
  }
  b -= 384;
  if (b < 64) {
    const int i = b * 256 + t;
    const int k = i >> 7, n = i & 127;
    Wh1t[(size_t)(k >> 3) * 1024 + n * 8 + (k & 7)] = f2bf(Wh1[i]);
    return;
  }
  b -= 64;
  if (b < 64) {
    const int i = b * 256 + t;
    const int k = i >> 7, n = i & 127;
    Wh2t[(size_t)(k >> 3) * 1024 + n * 8 + (k & 7)] = f2bf(Wh2[i]);
    return;
  }
  b -= 64;
  if (b < 256) {
    const int i = b * 256 + t;
    const int k = i >> 9, n = i & 511;
    Wm1t[(size_t)(k >> 3) * 4096 + n * 8 + (k & 7)] = f2bf(Wm1[i]);
    return;
  }
  b -= 256;
  if (b < 256) {
    const int i = b * 256 + t;
    const int k = i >> 7, n = i & 127;
    Wm2t[(size_t)(k >> 3) * 1024 + n * 8 + (k & 7)] = f2bf(Wm2[i]);
    return;
  }
  b -= 256;
  if (b < 3) {
    const int u = b * 256 + t;
    if (u >= 768) return;
    const int m = u / 384;
    const int r = u % 384;
    const float* batt = m ? batt1 : batt0;
    const float* avec = m ? a1 : a0;
    const float* bval = m ? bval1 : bval0;
    float* base = P + m * 384;
    if (r < 256) {
      const int h = r >> 6, hi = (r >> 5) & 1, q = (r >> 1) & 15, c = r & 1;
      const int rq = (q & 3) + 8 * (q >> 2) + 4 * hi;
      base[r] = c ? avec[h * 32 + rq] : batt[h * 32 + rq];
    } else {
      const int i = r - 256;
      const int g = i >> 5, hi = (i >> 4) & 1, q = i & 15;
      const int rq = (q & 3) + 8 * (q >> 2) + 4 * hi;
      base[256 + i] = bval[g * 32 + rq];
    }
    return;
  }
  b -= 3;
  {
    const int i = b * 256 + t;
    if (i < 32768) zbuf[i] = 0;
  }
}

// ---------------------------------------------------------------------------
// CSR build (validated R6/R9)
// ---------------------------------------------------------------------------
__global__ void csr_hist(const int* __restrict__ e0, const int* __restrict__ e1,
                         int* __restrict__ cnt0, int* __restrict__ cnt1)
{
  const int i = blockIdx.x * 256 + threadIdx.x;
  if (i < E_PP) atomicAdd(&cnt0[e0[E_PP + i]], 1);
  if (i < E_LP) atomicAdd(&cnt1[e1[E_LP + i]], 1);
}

__global__ void csr_scan2(const int* __restrict__ cnt0, int* __restrict__ off0,
                          const int* __restrict__ cnt1, int* __restrict__ off1)
{
  const int* cnt = blockIdx.x ? cnt1 : cnt0;
  int* off = blockIdx.x ? off1 : off0;
  __shared__ int ps[1024];
  const int t = threadIdx.x;
  int loc[8];
  int s = 0;
  #pragma unroll
  for (int i = 0; i < 8; ++i) { loc[i] = cnt[t * 8 + i]; s += loc[i]; }
  ps[t] = s;
  __syncthreads();
  for (int d = 1; d < 1024; d <<= 1) {
    int v = (t >= d) ? ps[t - d] : 0;
    __syncthreads();
    ps[t] += v;
    __syncthreads();
  }
  int ex = ps[t] - s;
  #pragma unroll
  for (int i = 0; i < 8; ++i) { off[t * 8 + i] = ex; ex += loc[i]; }
  if (t == 1023) off[8192] = ps[1023];
}

__global__ void csr_scat(const int* __restrict__ e0, const int* __restrict__ e1,
                         const int* __restrict__ off0, const int* __restrict__ off1,
                         int* __restrict__ cur0, int* __restrict__ cur1,
                         int* __restrict__ pel0, int* __restrict__ pel1)
{
  const int i = blockIdx.x * 256 + threadIdx.x;
  if (i < E_PP) { int s = e0[E_PP + i]; pel0[i] = off0[s] + atomicAdd(&cur0[s], 1); }
  if (i < E_LP) { int s = e1[E_LP + i]; pel1[i] = off1[s] + atomicAdd(&cur1[s], 1); }
}

// ---------------------------------------------------------------------------
// Edge GATv2 (R18 structure; hybrid B path: att half staged in LDS (4KB,
// compacted), val half read directly from L2-resident Bt with 1-step reg
// prefetch. LDS traffic/step: 30KB -> 18KB.
// ---------------------------------------------------------------------------
template<int MODE>
__device__ __forceinline__ void edge_body(
    int blk, char* AsmS, char* BsmS, f32x4* epsLds,
    const float* __restrict__ Afeat, const float* __restrict__ prot,
    const float* __restrict__ eattr, const int* __restrict__ eidx,
    const int* __restrict__ pel,
    const ushort_t* __restrict__ Bt, const float* __restrict__ P,
    char* __restrict__ ev, float* __restrict__ eb)
{
  constexpr int K  = (MODE == 0) ? 576 : 384;
  constexpr int E  = (MODE == 0) ? E_PP : E_LP;
  constexpr int NT = K / 16;

  const int t    = threadIdx.x;      // 0..255
  const int lane = t & 63;
  const int w    = t >> 6;           // wave id
  const int gl   = w >> 1;           // edge-group 0/1
  const int role = w & 1;            // 0 = att, 1 = val
  const int col  = lane & 31;
  const int hi   = lane >> 5;
  const int eid  = blk * 64 + gl * 32 + col;
  const int pos  = pel[eid];

  const int srow = t >> 2;           // 0..63
  const int sq   = t & 3;
  const int seid = blk * 64 + srow;
  const int ssnk = eidx[E + seid];
  const float* sA;
  const float* sP;
  const float* sE = nullptr;
  if (MODE == 0) {
    sA = Afeat + (size_t)seid * 448 + sq * 4;
    sP = prot  + (size_t)ssnk * 128 + sq * 4;
  } else {
    sA = Afeat + (size_t)eidx[seid] * 128 + sq * 4;
    sP = prot  + (size_t)ssnk * 128 + sq * 4;
    sE = eattr + (size_t)seid * 128 + sq * 4;
  }
  auto sptr = [&](int s) -> const float* {
    const int k0 = s * 16;
    if (MODE == 0) return (k0 < 448) ? (sA + k0) : (sP + (k0 - 448));
    const int r = k0 >> 7, kk = k0 & 127;
    return (r == 0) ? (sA + kk) : (r == 1) ? (sP + kk) : (sE + kk);
  };
  char* const wrA = AsmS + (srow >> 5) * 1536 + (srow & 31) * 48 + sq * 8;
  const char* const rdA = AsmS + gl * 1536 + col * 48 + hi * 16;

  const u32x4* btv = (const u32x4*)Bt;
  // B staging (att half only): thread t owns compact slot t <- global chunk
  // c = (t<128 ? t : 256+(t-128)). 4KB/slice, contiguous writes.
  const int bchunk = ((t >> 7) << 8) | (t & 127);
  char* const wrB = BsmS + t * 16;
  // att read: compact addr hi*2048 + col*16 (+ nbl*512), buffer stride 4096
  const char* const rdB = BsmS + hi * 2048 + col * 16;
  // val read: direct from Bt (L2): base + s*8192 + nbl*512
  const char* const vfp = (const char*)Bt + 2048 + hi * 4096 + col * 16;

  f32x16 acc[4];
  #pragma unroll
  for (int i = 0; i < 4; ++i) acc[i] = (f32x16)(0.0f);

  f32x4 gA1, gA2;
  u32x4 gB1, gB2;
  u32x4 vB[2][4];
  {
    f32x4 g0 = *(const f32x4*)sptr(0);
    u32x4 b0 = btv[bchunk];
    gA1 = *(const f32x4*)sptr(1);
    gB1 = btv[512 + bchunk];
    if (role) {
      #pragma unroll
      for (int nbl = 0; nbl < 4; ++nbl)
        vB[0][nbl] = *(const u32x4*)(vfp + nbl * 512);
    }
    u32x2 pk;
    pk.x = cvt_pk_bf16(g0.x, g0.y);
    pk.y = cvt_pk_bf16(g0.z, g0.w);
    *(u32x2*)wrA = pk;
    *(u32x4*)wrB = b0;
  }
  __syncthreads();

  #pragma unroll
  for (int s = 0; s < NT; ++s) {
    const int p = s & 1;
    if (s + 2 < NT) {
      gA2 = *(const f32x4*)sptr(s + 2);
      gB2 = btv[(size_t)(s + 2) * 512 + bchunk];
    }
    if (role && s + 1 < NT) {
      #pragma unroll
      for (int nbl = 0; nbl < 4; ++nbl)
        vB[(s + 1) & 1][nbl] = *(const u32x4*)(vfp + (size_t)(s + 1) * 8192 + nbl * 512);
    }

    frag32 af;
    af.v = *(const u32x4*)(rdA + p * 3072);
    if (role == 0) {
      const char* bs = rdB + p * 4096;
      #pragma unroll
      for (int nbl = 0; nbl < 4; ++nbl) {
        frag32 bf;
        bf.v = *(const u32x4*)(bs + nbl * 512);
        acc[nbl] = __builtin_amdgcn_mfma_f32_32x32x16_bf16(bf.s, af.s, acc[nbl], 0, 0, 0);
      }
    } else {
      #pragma unroll
      for (int nbl = 0; nbl < 4; ++nbl) {
        frag32 bf;
        bf.v = vB[s & 1][nbl];
        acc[nbl] = __builtin_amdgcn_mfma_f32_32x32x16_bf16(bf.s, af.s, acc[nbl], 0, 0, 0);
      }
    }

    if (s + 1 < NT) {
      u32x2 pk;
      pk.x = cvt_pk_bf16(gA1.x, gA1.y);
      pk.y = cvt_pk_bf16(gA1.z, gA1.w);
      *(u32x2*)(wrA + (p ^ 1) * 3072) = pk;
      *(u32x4*)(wrB + (p ^ 1) * 4096) = gB1;
    }
    gA1 = gA2; gB1 = gB2;
    // barrier WITHOUT vmcnt drain (validated R12): prefetch loads stay in
    // flight; LDS writes visible via lgkmcnt(0).
    asm volatile("s_waitcnt lgkmcnt(0)\n\ts_barrier" ::: "memory");
  }

  if (role == 0) {
    // ---- att epilogue (validated R4/R6/R9/R12) ----
    float ep[4];
    #pragma unroll
    for (int h = 0; h < 4; ++h) {
      const f32x4* tp = (const f32x4*)(P + (h * 2 + hi) * 32);
      float partial = 0.f;
      #pragma unroll
      for (int q = 0; q < 16; q += 2) {
        const f32x4 ba = tp[q >> 1];
        float x0 = acc[h][q]     + ba.x; x0 = (x0 > 0.f) ? x0 : 0.2f * x0;
        float x1 = acc[h][q + 1] + ba.z; x1 = (x1 > 0.f) ? x1 : 0.2f * x1;
        partial = fmaf(x0, ba.y, partial);
        partial = fmaf(x1, ba.w, partial);
      }
      const float full = partial + __shfl_xor(partial, 32, 64);
      ep[h] = __expf(full);            // no max-sub: logits bounded
    }
    f32x2 ef2;
    ef2.x = hi ? ep[2] : ep[0];
    ef2.y = hi ? ep[3] : ep[1];
    *(f32x2*)(eb + (size_t)pos * 4 + 2 * hi) = ef2;
    if (hi == 0) {
      f32x4 ef = {ep[0], ep[1], ep[2], ep[3]};
      epsLds[gl * 32 + col] = ef;
    }
  }
  __syncthreads();
  if (role == 1) {
    // ---- val epilogue: streaming ev store (validated R6/R9/R12) ----
    const f32x4 ep4 = epsLds[gl * 32 + col];
    const float* bvp = P + 256;
    char* row = ev + (size_t)pos * 256;
    #pragma unroll
    for (int g = 0; g < 4; ++g) {
      const float wgt = ep4[g];
      const float* bv = bvp + (g * 2 + hi) * 16;
      #pragma unroll
      for (int s = 0; s < 4; ++s) {
        const float v0 = (acc[g][s * 4 + 0] + bv[s * 4 + 0]) * wgt;
        const float v1 = (acc[g][s * 4 + 1] + bv[s * 4 + 1]) * wgt;
        const float v2 = (acc[g][s * 4 + 2] + bv[s * 4 + 2]) * wgt;
        const float v3 = (acc[g][s * 4 + 3] + bv[s * 4 + 3]) * wgt;
        u32x2 pk;
        pk.x = cvt_pk_bf16(v0, v1);
        pk.y = cvt_pk_bf16(v2, v3);
        *(u32x2*)(row + g * 64 + s * 16 + hi * 8) = pk;
      }
    }
  }
}

__global__ __launch_bounds__(256, 3)
void edge_gat15(const float* __restrict__ src_exp, const float* __restrict__ prot,
                const float* __restrict__ lig, const float* __restrict__ eattr,
                const int* __restrict__ eidx0, const int* __restrict__ eidx1,
                const int* __restrict__ pel0, const int* __restrict__ pel1,
                const ushort_t* __restrict__ Bt0, const ushort_t* __restrict__ Bt1,
                const float* __restrict__ P,
                char* __restrict__ ev0, float* __restrict__ eb0,
                char* __restrict__ ev1, float* __restrict__ eb1)
{
  __shared__ alignas(16) char AsmS[2 * 3072];   // 6 KB A
  __shared__ alignas(16) char BsmS[2 * 4096];   // 8 KB B (att half only)
  __shared__ f32x4 eps[64];
  const int bid = blockIdx.x;
  if (bid < NB0)
    edge_body<0>(bid, AsmS, BsmS, eps, src_exp, prot, nullptr, eidx0, pel0,
                 Bt0, P, ev0, eb0);
  else
    edge_body<1>(bid - NB0, AsmS, BsmS, eps, lig, prot, eattr, eidx1, pel1,
                 Bt1, P + 384, ev1, eb1);
}

// ---------------------------------------------------------------------------
// seg_gather (validated R14)
// ---------------------------------------------------------------------------
__global__ __launch_bounds__(256)
void seg_gather(const int* __restrict__ off0, const char* __restrict__ ev0,
                const float* __restrict__ eb0,
                const int* __restrict__ off1, const char* __restrict__ ev1,
                const float* __restrict__ eb1,
                ushort_t* __restrict__ att)
{
  __shared__ float xch[8 * 16 * 18];   // [node][j][va0x8|va1x8|d0|d1]
  const int t    = threadIdx.x;
  const int nl   = t >> 5;
  const int half = (t >> 4) & 1;
  const int j    = t & 15;
  const int n    = blockIdx.x * 8 + nl;

  float va0[8] = {0,0,0,0,0,0,0,0}, va1[8] = {0,0,0,0,0,0,0,0};
  float d0 = 0.f, d1 = 0.f;
  {
    const int end = off0[n + 1];
    for (int it = off0[n] + half; it < end; it += 2) {
      const u32x4 r = *(const u32x4*)(ev0 + (size_t)it * 256 + j * 16);
      d0 += eb0[(size_t)it * 4 + (j >> 2)];
      #pragma unroll
      for (int i = 0; i < 4; ++i) {
        va0[2 * i]     += bf_lo(r[i]);
        va0[2 * i + 1] += bf_hi(r[i]);
      }
    }
  }
  {
    const int end = off1[n + 1];
    for (int it = off1[n] + half; it < end; it += 2) {
      const u32x4 r = *(const u32x4*)(ev1 + (size_t)it * 256 + j * 16);
      d1 += eb1[(size_t)it * 4 + (j >> 2)];
      #pragma unroll
      for (int i = 0; i < 4; ++i) {
        va1[2 * i]     += bf_lo(r[i]);
        va1[2 * i + 1] += bf_hi(r[i]);
      }
    }
  }
  float* slot = xch + (nl * 16 + j) * 18;
  if (half) {
    #pragma unroll
    for (int i = 0; i < 8; ++i) { slot[i] = va0[i]; slot[8 + i] = va1[i]; }
    slot[16] = d0; slot[17] = d1;
  }
  __syncthreads();
  if (!half) {
    #pragma unroll
    for (int i = 0; i < 8; ++i) { va0[i] += slot[i]; va1[i] += slot[8 + i]; }
    d0 += slot[16]; d1 += slot[17];
    const float inv0 = 1.f / (d0 + 1e-9f);
    const float inv1 = 1.f / (d1 + 1e-9f);
    float res[8];
    #pragma unroll
    for (int i = 0; i < 8; ++i) res[i] = va0[i] * inv0 + va1[i] * inv1;
    u32x4 pk;
    pk.x = cvt_pk_bf16(res[0], res[1]);
    pk.y = cvt_pk_bf16(res[2], res[3]);
    pk.z = cvt_pk_bf16(res[4], res[5]);
    pk.w = cvt_pk_bf16(res[6], res[7]);
    *(u32x4*)(att + (size_t)n * 128 + j * 8) = pk;
  }
}

// ---------------------------------------------------------------------------
// LN over 16 rows of 128 (validated R2; stride-parameterized)
// ---------------------------------------------------------------------------
__device__ inline void ln_rows16(const float* __restrict__ src, int ss,
                                 float* __restrict__ dst, int ds,
                                 const float* __restrict__ g, const float* __restrict__ b,
                                 const int t)
{
  const int lane = t & 63;
  const int n    = (t >> 6) * 4 + (lane >> 4);
  const int c0   = (lane & 15) * 8;
  f32x4 va = *(const f32x4*)&src[n * ss + c0];
  f32x4 vb = *(const f32x4*)&src[n * ss + c0 + 4];
  float s = va.x + va.y + va.z + va.w + vb.x + vb.y + vb.z + vb.w;
  float q = va.x * va.x + va.y * va.y + va.z * va.z + va.w * va.w
          + vb.x * vb.x + vb.y * vb.y + vb.z * vb.z + vb.w * vb.w;
  #pragma unroll
  for (int m = 1; m < 16; m <<= 1) {
    s += __shfl_xor(s, m, 64);
    q += __shfl_xor(q, m, 64);
  }
  const float mean = s * 0.0078125f;
  const float var  = q * 0.0078125f - mean * mean;
  const float r    = rsqrtf(var + 1e-5f);
  f32x4 oa, ob;
  oa.x = (va.x - mean) * r * g[c0 + 0] + b[c0 + 0];
  oa.y = (va.y - mean) * r * g[c0 + 1] + b[c0 + 1];
  oa.z = (va.z - mean) * r * g[c0 + 2] + b[c0 + 2];
  oa.w = (va.w - mean) * r * g[c0 + 3] + b[c0 + 3];
  ob.x = (vb.x - mean) * r * g[c0 + 4] + b[c0 + 4];
  ob.y = (vb.y - mean) * r * g[c0 + 5] + b[c0 + 5];
  ob.z = (vb.z - mean) * r * g[c0 + 6] + b[c0 + 6];
  ob.w = (vb.w - mean) * r * g[c0 + 7] + b[c0 + 7];
  *(f32x4*)&dst[n * ds + c0]     = oa;
  *(f32x4*)&dst[n * ds + c0 + 4] = ob;
}

// ---------------------------------------------------------------------------
// Node update, MFMA version (validated R13/R14)
// ---------------------------------------------------------------------------
__global__ __launch_bounds__(256, 2)
void node_mfma(const ushort_t* __restrict__ att,
               const float* __restrict__ prot,
               const ushort_t* __restrict__ Wh1t, const float* __restrict__ bh1,
               const ushort_t* __restrict__ Wh2t, const float* __restrict__ bh2,
               const float* __restrict__ ln1g, const float* __restrict__ ln1b,
               const ushort_t* __restrict__ Wm1t, const float* __restrict__ bm1,
               const ushort_t* __restrict__ Wm2t, const float* __restrict__ bm2,
               const float* __restrict__ ln2g, const float* __restrict__ ln2b,
               float* __restrict__ out)
{
  __shared__ alignas(16) char xA[8 * 1536];        // 12 KB bf16 A-tile [8][32x48B]
  __shared__ alignas(16) char r2[32 * XSTR * 4];   // ~16.9 KB: fp32 scratch / t3A
  const int t    = threadIdx.x;
  const int lane = t & 63;
  const int w    = t >> 6;     // tile id 0..3
  const int l31  = lane & 31;
  const int hi   = lane >> 5;
  const int m0   = blockIdx.x * 32;
  float* xs = (float*)r2;
  char*  t3A = r2;

  // ---- phase 1: copy combined att (bf16) into the LDS A-tile ----
  #pragma unroll
  for (int it = 0; it < 2; ++it) {
    const int u  = t + it * 256;
    const int nl = u >> 4, j = u & 15;
    const u32x4 pk = *(const u32x4*)(att + (size_t)(m0 + nl) * 128 + j * 8);
    *(u32x4*)(xA + (j >> 1) * 1536 + nl * 48 + (j & 1) * 16) = pk;
  }
  __syncthreads();

  const char* rdA = xA + l31 * 48 + hi * 16;
  f32x16 acc;

  // ---- phase 2: t1 = gelu(xa @ Wh1 + bh1) -> xA (overwrite) ----
  acc = (f32x16)(0.0f);
  #pragma unroll
  for (int s = 0; s < 8; ++s) {
    frag32 af, bf;
    af.v = *(const u32x4*)(rdA + s * 1536);
    bf.v = *(const u32x4*)((const char*)Wh1t + (2 * s + hi) * 2048 + (w * 32 + l31) * 16);
    acc = __builtin_amdgcn_mfma_f32_32x32x16_bf16(bf.s, af.s, acc, 0, 0, 0);
  }
  __syncthreads();
  #pragma unroll
  for (int jr = 0; jr < 4; ++jr) {
    const int c0 = w * 32 + jr * 8 + 4 * hi;
    const f32x4 bb = *(const f32x4*)(bh1 + c0);
    const float v0 = gelu_tanh(acc[4 * jr + 0] + bb.x);
    const float v1 = gelu_tanh(acc[4 * jr + 1] + bb.y);
    const float v2 = gelu_tanh(acc[4 * jr + 2] + bb.z);
    const float v3 = gelu_tanh(acc[4 * jr + 3] + bb.w);
    u32x2 pk;
    pk.x = cvt_pk_bf16(v0, v1);
    pk.y = cvt_pk_bf16(v2, v3);
    *(u32x2*)(xA + (c0 >> 4) * 1536 + l31 * 48 + ((c0 >> 3) & 1) * 16 + (c0 & 7) * 2) = pk;
  }
  __syncthreads();

  // ---- phase 3: x = prot + t1 @ Wh2 + bh2 -> LN1 -> xA ----
  acc = (f32x16)(0.0f);
  #pragma unroll
  for (int s = 0; s < 8; ++s) {
    frag32 af, bf;
    af.v = *(const u32x4*)(rdA + s * 1536);
    bf.v = *(const u32x4*)((const char*)Wh2t + (2 * s + hi) * 2048 + (w * 32 + l31) * 16);
    acc = __builtin_amdgcn_mfma_f32_32x32x16_bf16(bf.s, af.s, acc, 0, 0, 0);
  }
  __syncthreads();
  #pragma unroll
  for (int q = 0; q < 16; ++q) {
    const int col = w * 32 + (q & 3) + 8 * (q >> 2) + 4 * hi;
    xs[l31 * XSTR + col] = acc[q];
  }
  __syncthreads();
  #pragma unroll
  for (int it = 0; it < 4; ++it) {
    const int u = t + it * 256;            // f32x4 unit: 32*32 = 1024
    const int row = u >> 5, c4 = (u & 31) * 4;
    f32x4 v = *(f32x4*)&xs[row * XSTR + c4];
    const f32x4 p = *(const f32x4*)&prot[(size_t)(m0 + row) * 128 + c4];
    const f32x4 b = *(const f32x4*)&bh2[c4];
    v += p + b;
    *(f32x4*)&xs[row * XSTR + c4] = v;
  }
  __syncthreads();
  ln_rows16(xs, XSTR, xs, XSTR, ln1g, ln1b, t);
  ln_rows16(xs + 16 * XSTR, XSTR, xs + 16 * XSTR, XSTR, ln1g, ln1b, t);
  __syncthreads();
  #pragma unroll
  for (int it = 0; it < 4; ++it) {
    const int u = t + it * 256;
    const int row = u >> 5, c4 = (u & 31) * 4;
    const f32x4 v = *(const f32x4*)&xs[row * XSTR + c4];
    u32x2 pk;
    pk.x = cvt_pk_bf16(v.x, v.y);
    pk.y = cvt_pk_bf16(v.z, v.w);
    *(u32x2*)(xA + (c4 >> 4) * 1536 + row * 48 + ((c4 >> 3) & 1) * 16 + (c4 & 7) * 2) = pk;
  }
  __syncthreads();

  // ---- phases 4+5 chunked: t3 = gelu(x @ Wm1 + bm1); pre += t3 @ Wm2 ----
  f32x16 acc5 = (f32x16)(0.0f);
  for (int ch = 0; ch < 4; ++ch) {
    f32x16 a4 = (f32x16)(0.0f);
    #pragma unroll
    for (int s = 0; s < 8; ++s) {
      frag32 af, bf;
      af.v = *(const u32x4*)(rdA + s * 1536);
      bf.v = *(const u32x4*)((const char*)Wm1t + (2 * s + hi) * 8192
                             + (ch * 128 + w * 32 + l31) * 16);
      a4 = __builtin_amdgcn_mfma_f32_32x32x16_bf16(bf.s, af.s, a4, 0, 0, 0);
    }
    __syncthreads();   // prior readers of r2 (xs / prev t3A) done
    #pragma unroll
    for (int jr = 0; jr < 4; ++jr) {
      const int c0 = w * 32 + jr * 8 + 4 * hi;
      const f32x4 bb = *(const f32x4*)(bm1 + ch * 128 + c0);
      const float v0 = gelu_tanh(a4[4 * jr + 0] + bb.x);
      const float v1 = gelu_tanh(a4[4 * jr + 1] + bb.y);
      const float v2 = gelu_tanh(a4[4 * jr + 2] + bb.z);
      const float v3 = gelu_tanh(a4[4 * jr + 3] + bb.w);
      u32x2 pk;
      pk.x = cvt_pk_bf16(v0, v1);
      pk.y = cvt_pk_bf16(v2, v3);
      *(u32x2*)(t3A + (c0 >> 4) * 1536 + l31 * 48 + ((c0 >> 3) & 1) * 16 + (c0 & 7) * 2) = pk;
    }
    __syncthreads();
    #pragma unroll
    for (int s = 0; s < 8; ++s) {
      frag32 af, bf;
      af.v = *(const u32x4*)(t3A + s * 1536 + l31 * 48 + hi * 16);
      bf.v = *(const u32x4*)((const char*)Wm2t + (ch * 16 + 2 * s + hi) * 2048
                             + (w * 32 + l31) * 16);
      acc5 = __builtin_amdgcn_mfma_f32_32x32x16_bf16(bf.s, af.s, acc5, 0, 0, 0);
    }
    __syncthreads();
  }

  // ---- epilogue: pre = x + acc5 + bm2 -> LN2 -> out ----
  #pragma unroll
  for (int q = 0; q < 16; ++q) {
    const int col = w * 32 + (q & 3) + 8 * (q >> 2) + 4 * hi;
    xs[l31 * XSTR + col] = acc5[q];
  }
  __syncthreads();
  #pragma unroll
  for (int it = 0; it < 4; ++it) {
    const int u = t + it * 256;
    const int row = u >> 5, c4 = (u & 31) * 4;
    f32x4 v = *(f32x4*)&xs[row * XSTR + c4];
    const u32x2 xx = *(const u32x2*)(xA + (c4 >> 4) * 1536 + row * 48
                                     + ((c4 >> 3) & 1) * 16 + (c4 & 7) * 2);
    const f32x4 b = *(const f32x4*)&bm2[c4];
    v.x += bf_lo(xx.x) + b.x;
    v.y += bf_hi(xx.x) + b.y;
    v.z += bf_lo(xx.y) + b.z;
    v.w += bf_hi(xx.y) + b.w;
    *(f32x4*)&xs[row * XSTR + c4] = v;
  }
  __syncthreads();
  ln_rows16(xs, XSTR, out + (size_t)m0 * 128, 128, ln2g, ln2b, t);
  ln_rows16(xs + 16 * XSTR, XSTR, out + (size_t)(m0 + 16) * 128, 128, ln2g, ln2b, t);
}

// ---------------------------------------------------------------------------
extern "C" void kernel_launch(void* const* d_in, const int* in_sizes, int n_in,
                              void* d_out, int out_size, void* d_ws, size_t ws_size,
                              hipStream_t stream)
{
  const float* src_exp = (const float*)d_in[0];
  const float* prot    = (const float*)d_in[1];
  const float* pvec    = (const float*)d_in[2];
  const int*   eidx0   = (const int*)d_in[3];
  const float* lig     = (const float*)d_in[4];
  const float* eattr   = (const float*)d_in[5];
  const int*   eidx1   = (const int*)d_in[6];
  const float* Watt0 = (const float*)d_in[7];
  const float* batt0 = (const float*)d_in[8];
  const float* a0    = (const float*)d_in[9];
  const float* Wval0 = (const float*)d_in[10];
  const float* bval0 = (const float*)d_in[11];
  const float* Watt1 = (const float*)d_in[12];
  const float* batt1 = (const float*)d_in[13];
  const float* a1    = (const float*)d_in[14];
  const float* Wval1 = (const float*)d_in[15];
  const float* bval1 = (const float*)d_in[16];
  const float* Wh1  = (const float*)d_in[17];
  const float* bh1  = (const float*)d_in[18];
  const float* Wh2  = (const float*)d_in[19];
  const float* bh2  = (const float*)d_in[20];
  const float* ln1g = (const float*)d_in[21];
  const float* ln1b = (const float*)d_in[22];
  const float* Wm1  = (const float*)d_in[23];
  const float* bm1  = (const float*)d_in[24];
  const float* Wm2  = (const float*)d_in[25];
  const float* bm2  = (const float*)d_in[26];
  const float* ln2g = (const float*)d_in[27];
  const float* ln2b = (const float*)d_in[28];

  char* w = (char*)d_ws;
  size_t o = 0;
  auto take = [&](size_t b) -> void* {
    void* p = w + o;
    o += (b + 255) & ~(size_t)255;
    return p;
  };
  int* cnt0 = (int*)take(8192 * 4);   // cnt0,cnt1,cur0,cur1 contiguous (zeroed in prep)
  int* cnt1 = (int*)take(8192 * 4);
  int* cur0 = (int*)take(8192 * 4);
  int* cur1 = (int*)take(8192 * 4);
  int* off0 = (int*)take(8193 * 4);
  int* off1 = (int*)take(8193 * 4);
  int* pel0 = (int*)take((size_t)E_PP * 4);
  int* pel1 = (int*)take((size_t)E_LP * 4);
  ushort_t* Bt0 = (ushort_t*)take((size_t)576 * 256 * 2);
  ushort_t* Bt1 = (ushort_t*)take((size_t)384 * 256 * 2);
  ushort_t* Wh1t = (ushort_t*)take((size_t)128 * 128 * 2);
  ushort_t* Wh2t = (ushort_t*)take((size_t)128 * 128 * 2);
  ushort_t* Wm1t = (ushort_t*)take((size_t)128 * 512 * 2);
  ushort_t* Wm2t = (ushort_t*)take((size_t)512 * 128 * 2);
  float* P = (float*)take(768 * 4);
  ushort_t* att = (ushort_t*)take((size_t)N_PROT * 128 * 2);
  char*  ev0 = (char*)take((size_t)E_PP * 256);
  char*  ev1 = (char*)take((size_t)E_LP * 256);
  float* eb0 = (float*)take((size_t)E_PP * 16);
  float* eb1 = (float*)take((size_t)E_LP * 16);

  prep_all<<<1731, 256, 0, stream>>>(Watt0, Wval0, Watt1, Wval1,
                                     Wh1, Wh2, Wm1, Wm2,
                                     batt0, a0, bval0, batt1, a1, bval1,
                                     Bt0, Bt1, Wh1t, Wh2t, Wm1t, Wm2t, P, cnt0);

  csr_hist<<<E_PP / 256, 256, 0, stream>>>(eidx0, eidx1, cnt0, cnt1);
  csr_scan2<<<2, 1024, 0, stream>>>(cnt0, off0, cnt1, off1);
  csr_scat<<<E_PP / 256, 256, 0, stream>>>(eidx0, eidx1, off0, off1,
                                           cur0, cur1, pel0, pel1);

  edge_gat15<<<NB0 + NB1, 256, 0, stream>>>(
      src_exp, prot, lig, eattr, eidx0, eidx1, pel0, pel1, Bt0, Bt1, P,
      ev0, eb0, ev1, eb1);

  seg_gather<<<N_PROT / 8, 256, 0, stream>>>(off0, ev0, eb0, off1, ev1, eb1, att);

  node_mfma<<<N_PROT / 32, 256, 0, stream>>>(
      att, prot,
      Wh1t, bh1, Wh2t, bh2, ln1g, ln1b,
      Wm1t, bm1, Wm2t, bm2, ln2g, ln2b, (float*)d_out);

  hipMemcpyAsync((float*)d_out + (size_t)N_PROT * 128, pvec,
                 (size_t)N_PROT * 12 * sizeof(float), hipMemcpyDeviceToDevice, stream);
}

// Round 20
// 257.398 us; speedup vs baseline: 1.0278x; 1.0278x over previous
//
#include <hip/hip_runtime.h>

#define N_PROT 8192
#define E_PP   163840
#define E_LP   81920
#define NB0    (E_PP / 64)   // 2560 pp blocks (64 edges each)
#define NB1    (E_LP / 64)   // 1280 lp blocks
#define XSTR   132           // padded fp32 row stride in node scratch

typedef float        f32x2  __attribute__((ext_vector_type(2)));
typedef float        f32x4  __attribute__((ext_vector_type(4)));
typedef float        f32x16 __attribute__((ext_vector_type(16)));
typedef unsigned int u32x2  __attribute__((ext_vector_type(2)));
typedef unsigned int u32x4  __attribute__((ext_vector_type(4)));
typedef short        s16x8  __attribute__((ext_vector_type(8)));
typedef unsigned short ushort_t;

union frag32 { u32x4 v; s16x8 s; };

__device__ inline unsigned short f2bf(float f) {
  unsigned int u = __float_as_uint(f);
  u = u + 0x7FFFu + ((u >> 16) & 1u);   // RTNE
  return (unsigned short)(u >> 16);
}

__device__ inline unsigned int cvt_pk_bf16(float lo, float hi) {
  unsigned int r;
  asm("v_cvt_pk_bf16_f32 %0, %1, %2" : "=v"(r) : "v"(lo), "v"(hi));
  return r;
}

__device__ inline float bf_lo(unsigned int u) { return __uint_as_float(u << 16); }
__device__ inline float bf_hi(unsigned int u) { return __uint_as_float(u & 0xffff0000u); }

__device__ inline float gelu_tanh(float x) {
  const float c0 = 0.7978845608028654f;
  float inner = c0 * (x + 0.044715f * x * x * x);
  return 0.5f * x * (1.0f + tanhf(inner));
}

// ---------------------------------------------------------------------------
// prep_all (validated R14)
// ---------------------------------------------------------------------------
__global__ void prep_all(const float* __restrict__ Watt0, const float* __restrict__ Wval0,
                         const float* __restrict__ Watt1, const float* __restrict__ Wval1,
                         const float* __restrict__ Wh1, const float* __restrict__ Wh2,
                         const float* __restrict__ Wm1, const float* __restrict__ Wm2,
                         const float* __restrict__ batt0, const float* __restrict__ a0,
                         const float* __restrict__ bval0,
                         const float* __restrict__ batt1, const float* __restrict__ a1,
                         const float* __restrict__ bval1,
                         ushort_t* __restrict__ Bt0, ushort_t* __restrict__ Bt1,
                         ushort_t* __restrict__ Wh1t, ushort_t* __restrict__ Wh2t,
                         ushort_t* __restrict__ Wm1t, ushort_t* __restrict__ Wm2t,
                         float* __restrict__ P, int* __restrict__ zbuf)
{
  int b = blockIdx.x;
  const int t = threadIdx.x;
  if (b < 576) {
    const int i = b * 256 + t;
    const int k = i >> 8, n = i & 255;
    const float v = (n < 128) ? Watt0[(size_t)k * 128 + n] : Wval0[(size_t)k * 128 + (n - 128)];
    Bt0[(size_t)(k >> 3) * 2048 + n * 8 + (k & 7)] = f2bf(v);
    return;
  }
  b -= 576;
  if (b < 384) {
    const int i = b * 256 + t;
    const int k = i >> 8, n = i & 255;
    const float v = (n < 128) ? Watt1[(size_t)k * 128 + n] : Wval1[(size_t)k * 128 + (n - 128)];
    Bt1[(size_t)(k >> 3) * 2048 + n * 8 + (k & 7)] = f2bf(v);
    return;
  }
  b -= 384;
  if (b < 64) {
    const int i = b * 256 + t;
    const int k = i >> 7, n = i & 127;
    Wh1t[(size_t)(k >> 3) * 1024 + n * 8 + (k & 7)] = f2bf(Wh1[i]);
    return;
  }
  b -= 64;
  if (b < 64) {
    const int i = b * 256 + t;
    const int k = i >> 7, n = i & 127;
    Wh2t[(size_t)(k >> 3) * 1024 + n * 8 + (k & 7)] = f2bf(Wh2[i]);
    return;
  }
  b -= 64;
  if (b < 256) {
    const int i = b * 256 + t;
    const int k = i >> 9, n = i & 511;
    Wm1t[(size_t)(k >> 3) * 4096 + n * 8 + (k & 7)] = f2bf(Wm1[i]);
    return;
  }
  b -= 256;
  if (b < 256) {
    const int i = b * 256 + t;
    const int k = i >> 7, n = i & 127;
    Wm2t[(size_t)(k >> 3) * 1024 + n * 8 + (k & 7)] = f2bf(Wm2[i]);
    return;
  }
  b -= 256;
  if (b < 3) {
    const int u = b * 256 + t;
    if (u >= 768) return;
    const int m = u / 384;
    const int r = u % 384;
    const float* batt = m ? batt1 : batt0;
    const float* avec = m ? a1 : a0;
    const float* bval = m ? bval1 : bval0;
    float* base = P + m * 384;
    if (r < 256) {
      const int h = r >> 6, hi = (r >> 5) & 1, q = (r >> 1) & 15, c = r & 1;
      const int rq = (q & 3) + 8 * (q >> 2) + 4 * hi;
      base[r] = c ? avec[h * 32 + rq] : batt[h * 32 + rq];
    } else {
      const int i = r - 256;
      const int g = i >> 5, hi = (i >> 4) & 1, q = i & 15;
      const int rq = (q & 3) + 8 * (q >> 2) + 4 * hi;
      base[256 + i] = bval[g * 32 + rq];
    }
    return;
  }
  b -= 3;
  {
    const int i = b * 256 + t;
    if (i < 32768) zbuf[i] = 0;
  }
}

// ---------------------------------------------------------------------------
// CSR build (validated R6/R9)
// ---------------------------------------------------------------------------
__global__ void csr_hist(const int* __restrict__ e0, const int* __restrict__ e1,
                         int* __restrict__ cnt0, int* __restrict__ cnt1)
{
  const int i = blockIdx.x * 256 + threadIdx.x;
  if (i < E_PP) atomicAdd(&cnt0[e0[E_PP + i]], 1);
  if (i < E_LP) atomicAdd(&cnt1[e1[E_LP + i]], 1);
}

__global__ void csr_scan2(const int* __restrict__ cnt0, int* __restrict__ off0,
                          const int* __restrict__ cnt1, int* __restrict__ off1)
{
  const int* cnt = blockIdx.x ? cnt1 : cnt0;
  int* off = blockIdx.x ? off1 : off0;
  __shared__ int ps[1024];
  const int t = threadIdx.x;
  int loc[8];
  int s = 0;
  #pragma unroll
  for (int i = 0; i < 8; ++i) { loc[i] = cnt[t * 8 + i]; s += loc[i]; }
  ps[t] = s;
  __syncthreads();
  for (int d = 1; d < 1024; d <<= 1) {
    int v = (t >= d) ? ps[t - d] : 0;
    __syncthreads();
    ps[t] += v;
    __syncthreads();
  }
  int ex = ps[t] - s;
  #pragma unroll
  for (int i = 0; i < 8; ++i) { off[t * 8 + i] = ex; ex += loc[i]; }
  if (t == 1023) off[8192] = ps[1023];
}

__global__ void csr_scat(const int* __restrict__ e0, const int* __restrict__ e1,
                         const int* __restrict__ off0, const int* __restrict__ off1,
                         int* __restrict__ cur0, int* __restrict__ cur1,
                         int* __restrict__ pel0, int* __restrict__ pel1)
{
  const int i = blockIdx.x * 256 + threadIdx.x;
  if (i < E_PP) { int s = e0[E_PP + i]; pel0[i] = off0[s] + atomicAdd(&cur0[s], 1); }
  if (i < E_LP) { int s = e1[E_LP + i]; pel1[i] = off1[s] + atomicAdd(&cur1[s], 1); }
}

// ---------------------------------------------------------------------------
// Edge GATv2 (R18, validated best: R14 structure + conflict-free B staging)
// ---------------------------------------------------------------------------
template<int MODE>
__device__ __forceinline__ void edge_body(
    int blk, char* AsmS, char* BsmS, f32x4* epsLds,
    const float* __restrict__ Afeat, const float* __restrict__ prot,
    const float* __restrict__ eattr, const int* __restrict__ eidx,
    const int* __restrict__ pel,
    const ushort_t* __restrict__ Bt, const float* __restrict__ P,
    char* __restrict__ ev, float* __restrict__ eb)
{
  constexpr int K  = (MODE == 0) ? 576 : 384;
  constexpr int E  = (MODE == 0) ? E_PP : E_LP;
  constexpr int NT = K / 16;

  const int t    = threadIdx.x;      // 0..255
  const int lane = t & 63;
  const int w    = t >> 6;           // wave id
  const int gl   = w >> 1;           // edge-group 0/1
  const int role = w & 1;            // 0 = att, 1 = val
  const int col  = lane & 31;
  const int hi   = lane >> 5;
  const int eid  = blk * 64 + gl * 32 + col;
  const int pos  = pel[eid];

  const int srow = t >> 2;           // 0..63
  const int sq   = t & 3;
  const int seid = blk * 64 + srow;
  const int ssnk = eidx[E + seid];
  const float* sA;
  const float* sP;
  const float* sE = nullptr;
  if (MODE == 0) {
    sA = Afeat + (size_t)seid * 448 + sq * 4;
    sP = prot  + (size_t)ssnk * 128 + sq * 4;
  } else {
    sA = Afeat + (size_t)eidx[seid] * 128 + sq * 4;
    sP = prot  + (size_t)ssnk * 128 + sq * 4;
    sE = eattr + (size_t)seid * 128 + sq * 4;
  }
  auto sptr = [&](int s) -> const float* {
    const int k0 = s * 16;
    if (MODE == 0) return (k0 < 448) ? (sA + k0) : (sP + (k0 - 448));
    const int r = k0 >> 7, kk = k0 & 127;
    return (r == 0) ? (sA + kk) : (r == 1) ? (sP + kk) : (sE + kk);
  };
  char* const wrA = AsmS + (srow >> 5) * 1536 + (srow & 31) * 48 + sq * 8;
  const char* const rdA = AsmS + gl * 1536 + col * 48 + hi * 16;

  const u32x4* btv = (const u32x4*)Bt;
  // B staging: thread t owns 16B chunks t and 256+t of each 8KB slice.
  // Write addrs t*16 / 4096+t*16 -> contiguous per wave (conflict-free).
  char* const wrB = BsmS + t * 16;
  const char* const rdB = BsmS + role * 2048 + hi * 4096 + col * 16;

  f32x16 acc[4];
  #pragma unroll
  for (int i = 0; i < 4; ++i) acc[i] = (f32x16)(0.0f);

  f32x4 gA1, gA2;
  u32x4 gB1a, gB1b, gB2a, gB2b;
  {
    f32x4 g0 = *(const f32x4*)sptr(0);
    u32x4 b0a = btv[t], b0b = btv[256 + t];
    gA1  = *(const f32x4*)sptr(1);
    gB1a = btv[512 + t];
    gB1b = btv[512 + 256 + t];
    u32x2 pk;
    pk.x = cvt_pk_bf16(g0.x, g0.y);
    pk.y = cvt_pk_bf16(g0.z, g0.w);
    *(u32x2*)wrA = pk;
    *(u32x4*)(wrB)        = b0a;
    *(u32x4*)(wrB + 4096) = b0b;
  }
  __syncthreads();

  #pragma unroll
  for (int s = 0; s < NT; ++s) {
    const int p = s & 1;
    if (s + 2 < NT) {
      gA2  = *(const f32x4*)sptr(s + 2);
      gB2a = btv[(size_t)(s + 2) * 512 + t];
      gB2b = btv[(size_t)(s + 2) * 512 + 256 + t];
    }

    frag32 af;
    af.v = *(const u32x4*)(rdA + p * 3072);
    const char* bs = rdB + p * 8192;
    #pragma unroll
    for (int nbl = 0; nbl < 4; ++nbl) {
      frag32 bf;
      bf.v = *(const u32x4*)(bs + nbl * 512);
      // swapped operands (validated R4): C[outcol][edge]
      acc[nbl] = __builtin_amdgcn_mfma_f32_32x32x16_bf16(bf.s, af.s, acc[nbl], 0, 0, 0);
    }

    if (s + 1 < NT) {
      u32x2 pk;
      pk.x = cvt_pk_bf16(gA1.x, gA1.y);
      pk.y = cvt_pk_bf16(gA1.z, gA1.w);
      *(u32x2*)(wrA + (p ^ 1) * 3072) = pk;
      *(u32x4*)(wrB + (p ^ 1) * 8192)        = gB1a;
      *(u32x4*)(wrB + (p ^ 1) * 8192 + 4096) = gB1b;
    }
    gA1 = gA2; gB1a = gB2a; gB1b = gB2b;
    // barrier WITHOUT vmcnt drain (validated R12): prefetch loads stay in
    // flight; LDS writes visible via lgkmcnt(0).
    asm volatile("s_waitcnt lgkmcnt(0)\n\ts_barrier" ::: "memory");
  }

  if (role == 0) {
    // ---- att epilogue (validated R4/R6/R9/R12) ----
    float ep[4];
    #pragma unroll
    for (int h = 0; h < 4; ++h) {
      const f32x4* tp = (const f32x4*)(P + (h * 2 + hi) * 32);
      float partial = 0.f;
      #pragma unroll
      for (int q = 0; q < 16; q += 2) {
        const f32x4 ba = tp[q >> 1];
        float x0 = acc[h][q]     + ba.x; x0 = (x0 > 0.f) ? x0 : 0.2f * x0;
        float x1 = acc[h][q + 1] + ba.z; x1 = (x1 > 0.f) ? x1 : 0.2f * x1;
        partial = fmaf(x0, ba.y, partial);
        partial = fmaf(x1, ba.w, partial);
      }
      const float full = partial + __shfl_xor(partial, 32, 64);
      ep[h] = __expf(full);            // no max-sub: logits bounded
    }
    f32x2 ef2;
    ef2.x = hi ? ep[2] : ep[0];
    ef2.y = hi ? ep[3] : ep[1];
    *(f32x2*)(eb + (size_t)pos * 4 + 2 * hi) = ef2;
    if (hi == 0) {
      f32x4 ef = {ep[0], ep[1], ep[2], ep[3]};
      epsLds[gl * 32 + col] = ef;
    }
  }
  __syncthreads();
  if (role == 1) {
    // ---- val epilogue: streaming ev store (validated R6/R9/R12) ----
    const f32x4 ep4 = epsLds[gl * 32 + col];
    const float* bvp = P + 256;
    char* row = ev + (size_t)pos * 256;
    #pragma unroll
    for (int g = 0; g < 4; ++g) {
      const float wgt = ep4[g];
      const float* bv = bvp + (g * 2 + hi) * 16;
      #pragma unroll
      for (int s = 0; s < 4; ++s) {
        const float v0 = (acc[g][s * 4 + 0] + bv[s * 4 + 0]) * wgt;
        const float v1 = (acc[g][s * 4 + 1] + bv[s * 4 + 1]) * wgt;
        const float v2 = (acc[g][s * 4 + 2] + bv[s * 4 + 2]) * wgt;
        const float v3 = (acc[g][s * 4 + 3] + bv[s * 4 + 3]) * wgt;
        u32x2 pk;
        pk.x = cvt_pk_bf16(v0, v1);
        pk.y = cvt_pk_bf16(v2, v3);
        *(u32x2*)(row + g * 64 + s * 16 + hi * 8) = pk;
      }
    }
  }
}

__global__ __launch_bounds__(256, 3)
void edge_gat14(const float* __restrict__ src_exp, const float* __restrict__ prot,
                const float* __restrict__ lig, const float* __restrict__ eattr,
                const int* __restrict__ eidx0, const int* __restrict__ eidx1,
                const int* __restrict__ pel0, const int* __restrict__ pel1,
                const ushort_t* __restrict__ Bt0, const ushort_t* __restrict__ Bt1,
                const float* __restrict__ P,
                char* __restrict__ ev0, float* __restrict__ eb0,
                char* __restrict__ ev1, float* __restrict__ eb1)
{
  __shared__ alignas(16) char AsmS[2 * 3072];
  __shared__ alignas(16) char BsmS[2 * 8192];
  __shared__ f32x4 eps[64];
  const int bid = blockIdx.x;
  if (bid < NB0)
    edge_body<0>(bid, AsmS, BsmS, eps, src_exp, prot, nullptr, eidx0, pel0,
                 Bt0, P, ev0, eb0);
  else
    edge_body<1>(bid - NB0, AsmS, BsmS, eps, lig, prot, eattr, eidx1, pel1,
                 Bt1, P + 384, ev1, eb1);
}

// ---------------------------------------------------------------------------
// seg_gather (validated R14)
// ---------------------------------------------------------------------------
__global__ __launch_bounds__(256)
void seg_gather(const int* __restrict__ off0, const char* __restrict__ ev0,
                const float* __restrict__ eb0,
                const int* __restrict__ off1, const char* __restrict__ ev1,
                const float* __restrict__ eb1,
                ushort_t* __restrict__ att)
{
  __shared__ float xch[8 * 16 * 18];   // [node][j][va0x8|va1x8|d0|d1]
  const int t    = threadIdx.x;
  const int nl   = t >> 5;
  const int half = (t >> 4) & 1;
  const int j    = t & 15;
  const int n    = blockIdx.x * 8 + nl;

  float va0[8] = {0,0,0,0,0,0,0,0}, va1[8] = {0,0,0,0,0,0,0,0};
  float d0 = 0.f, d1 = 0.f;
  {
    const int end = off0[n + 1];
    for (int it = off0[n] + half; it < end; it += 2) {
      const u32x4 r = *(const u32x4*)(ev0 + (size_t)it * 256 + j * 16);
      d0 += eb0[(size_t)it * 4 + (j >> 2)];
      #pragma unroll
      for (int i = 0; i < 4; ++i) {
        va0[2 * i]     += bf_lo(r[i]);
        va0[2 * i + 1] += bf_hi(r[i]);
      }
    }
  }
  {
    const int end = off1[n + 1];
    for (int it = off1[n] + half; it < end; it += 2) {
      const u32x4 r = *(const u32x4*)(ev1 + (size_t)it * 256 + j * 16);
      d1 += eb1[(size_t)it * 4 + (j >> 2)];
      #pragma unroll
      for (int i = 0; i < 4; ++i) {
        va1[2 * i]     += bf_lo(r[i]);
        va1[2 * i + 1] += bf_hi(r[i]);
      }
    }
  }
  float* slot = xch + (nl * 16 + j) * 18;
  if (half) {
    #pragma unroll
    for (int i = 0; i < 8; ++i) { slot[i] = va0[i]; slot[8 + i] = va1[i]; }
    slot[16] = d0; slot[17] = d1;
  }
  __syncthreads();
  if (!half) {
    #pragma unroll
    for (int i = 0; i < 8; ++i) { va0[i] += slot[i]; va1[i] += slot[8 + i]; }
    d0 += slot[16]; d1 += slot[17];
    const float inv0 = 1.f / (d0 + 1e-9f);
    const float inv1 = 1.f / (d1 + 1e-9f);
    float res[8];
    #pragma unroll
    for (int i = 0; i < 8; ++i) res[i] = va0[i] * inv0 + va1[i] * inv1;
    u32x4 pk;
    pk.x = cvt_pk_bf16(res[0], res[1]);
    pk.y = cvt_pk_bf16(res[2], res[3]);
    pk.z = cvt_pk_bf16(res[4], res[5]);
    pk.w = cvt_pk_bf16(res[6], res[7]);
    *(u32x4*)(att + (size_t)n * 128 + j * 8) = pk;
  }
}

// ---------------------------------------------------------------------------
// LN over 16 rows of 128 (validated R2; stride-parameterized)
// ---------------------------------------------------------------------------
__device__ inline void ln_rows16(const float* __restrict__ src, int ss,
                                 float* __restrict__ dst, int ds,
                                 const float* __restrict__ g, const float* __restrict__ b,
                                 const int t)
{
  const int lane = t & 63;
  const int n    = (t >> 6) * 4 + (lane >> 4);
  const int c0   = (lane & 15) * 8;
  f32x4 va = *(const f32x4*)&src[n * ss + c0];
  f32x4 vb = *(const f32x4*)&src[n * ss + c0 + 4];
  float s = va.x + va.y + va.z + va.w + vb.x + vb.y + vb.z + vb.w;
  float q = va.x * va.x + va.y * va.y + va.z * va.z + va.w * va.w
          + vb.x * vb.x + vb.y * vb.y + vb.z * vb.z + vb.w * vb.w;
  #pragma unroll
  for (int m = 1; m < 16; m <<= 1) {
    s += __shfl_xor(s, m, 64);
    q += __shfl_xor(q, m, 64);
  }
  const float mean = s * 0.0078125f;
  const float var  = q * 0.0078125f - mean * mean;
  const float r    = rsqrtf(var + 1e-5f);
  f32x4 oa, ob;
  oa.x = (va.x - mean) * r * g[c0 + 0] + b[c0 + 0];
  oa.y = (va.y - mean) * r * g[c0 + 1] + b[c0 + 1];
  oa.z = (va.z - mean) * r * g[c0 + 2] + b[c0 + 2];
  oa.w = (va.w - mean) * r * g[c0 + 3] + b[c0 + 3];
  ob.x = (vb.x - mean) * r * g[c0 + 4] + b[c0 + 4];
  ob.y = (vb.y - mean) * r * g[c0 + 5] + b[c0 + 5];
  ob.z = (vb.z - mean) * r * g[c0 + 6] + b[c0 + 6];
  ob.w = (vb.w - mean) * r * g[c0 + 7] + b[c0 + 7];
  *(f32x4*)&dst[n * ds + c0]     = oa;
  *(f32x4*)&dst[n * ds + c0 + 4] = ob;
}

// ---------------------------------------------------------------------------
// Node update, MFMA version (validated R13/R14)
// ---------------------------------------------------------------------------
__global__ __launch_bounds__(256, 2)
void node_mfma(const ushort_t* __restrict__ att,
               const float* __restrict__ prot,
               const ushort_t* __restrict__ Wh1t, const float* __restrict__ bh1,
               const ushort_t* __restrict__ Wh2t, const float* __restrict__ bh2,
               const float* __restrict__ ln1g, const float* __restrict__ ln1b,
               const ushort_t* __restrict__ Wm1t, const float* __restrict__ bm1,
               const ushort_t* __restrict__ Wm2t, const float* __restrict__ bm2,
               const float* __restrict__ ln2g, const float* __restrict__ ln2b,
               float* __restrict__ out)
{
  __shared__ alignas(16) char xA[8 * 1536];        // 12 KB bf16 A-tile [8][32x48B]
  __shared__ alignas(16) char r2[32 * XSTR * 4];   // ~16.9 KB: fp32 scratch / t3A
  const int t    = threadIdx.x;
  const int lane = t & 63;
  const int w    = t >> 6;     // tile id 0..3
  const int l31  = lane & 31;
  const int hi   = lane >> 5;
  const int m0   = blockIdx.x * 32;
  float* xs = (float*)r2;
  char*  t3A = r2;

  // ---- phase 1: copy combined att (bf16) into the LDS A-tile ----
  #pragma unroll
  for (int it = 0; it < 2; ++it) {
    const int u  = t + it * 256;
    const int nl = u >> 4, j = u & 15;
    const u32x4 pk = *(const u32x4*)(att + (size_t)(m0 + nl) * 128 + j * 8);
    *(u32x4*)(xA + (j >> 1) * 1536 + nl * 48 + (j & 1) * 16) = pk;
  }
  __syncthreads();

  const char* rdA = xA + l31 * 48 + hi * 16;
  f32x16 acc;

  // ---- phase 2: t1 = gelu(xa @ Wh1 + bh1) -> xA (overwrite) ----
  acc = (f32x16)(0.0f);
  #pragma unroll
  for (int s = 0; s < 8; ++s) {
    frag32 af, bf;
    af.v = *(const u32x4*)(rdA + s * 1536);
    bf.v = *(const u32x4*)((const char*)Wh1t + (2 * s + hi) * 2048 + (w * 32 + l31) * 16);
    acc = __builtin_amdgcn_mfma_f32_32x32x16_bf16(bf.s, af.s, acc, 0, 0, 0);
  }
  __syncthreads();
  #pragma unroll
  for (int jr = 0; jr < 4; ++jr) {
    const int c0 = w * 32 + jr * 8 + 4 * hi;
    const f32x4 bb = *(const f32x4*)(bh1 + c0);
    const float v0 = gelu_tanh(acc[4 * jr + 0] + bb.x);
    const float v1 = gelu_tanh(acc[4 * jr + 1] + bb.y);
    const float v2 = gelu_tanh(acc[4 * jr + 2] + bb.z);
    const float v3 = gelu_tanh(acc[4 * jr + 3] + bb.w);
    u32x2 pk;
    pk.x = cvt_pk_bf16(v0, v1);
    pk.y = cvt_pk_bf16(v2, v3);
    *(u32x2*)(xA + (c0 >> 4) * 1536 + l31 * 48 + ((c0 >> 3) & 1) * 16 + (c0 & 7) * 2) = pk;
  }
  __syncthreads();

  // ---- phase 3: x = prot + t1 @ Wh2 + bh2 -> LN1 -> xA ----
  acc = (f32x16)(0.0f);
  #pragma unroll
  for (int s = 0; s < 8; ++s) {
    frag32 af, bf;
    af.v = *(const u32x4*)(rdA + s * 1536);
    bf.v = *(const u32x4*)((const char*)Wh2t + (2 * s + hi) * 2048 + (w * 32 + l31) * 16);
    acc = __builtin_amdgcn_mfma_f32_32x32x16_bf16(bf.s, af.s, acc, 0, 0, 0);
  }
  __syncthreads();
  #pragma unroll
  for (int q = 0; q < 16; ++q) {
    const int col = w * 32 + (q & 3) + 8 * (q >> 2) + 4 * hi;
    xs[l31 * XSTR + col] = acc[q];
  }
  __syncthreads();
  #pragma unroll
  for (int it = 0; it < 4; ++it) {
    const int u = t + it * 256;            // f32x4 unit: 32*32 = 1024
    const int row = u >> 5, c4 = (u & 31) * 4;
    f32x4 v = *(f32x4*)&xs[row * XSTR + c4];
    const f32x4 p = *(const f32x4*)&prot[(size_t)(m0 + row) * 128 + c4];
    const f32x4 b = *(const f32x4*)&bh2[c4];
    v += p + b;
    *(f32x4*)&xs[row * XSTR + c4] = v;
  }
  __syncthreads();
  ln_rows16(xs, XSTR, xs, XSTR, ln1g, ln1b, t);
  ln_rows16(xs + 16 * XSTR, XSTR, xs + 16 * XSTR, XSTR, ln1g, ln1b, t);
  __syncthreads();
  #pragma unroll
  for (int it = 0; it < 4; ++it) {
    const int u = t + it * 256;
    const int row = u >> 5, c4 = (u & 31) * 4;
    const f32x4 v = *(const f32x4*)&xs[row * XSTR + c4];
    u32x2 pk;
    pk.x = cvt_pk_bf16(v.x, v.y);
    pk.y = cvt_pk_bf16(v.z, v.w);
    *(u32x2*)(xA + (c4 >> 4) * 1536 + row * 48 + ((c4 >> 3) & 1) * 16 + (c4 & 7) * 2) = pk;
  }
  __syncthreads();

  // ---- phases 4+5 chunked: t3 = gelu(x @ Wm1 + bm1); pre += t3 @ Wm2 ----
  f32x16 acc5 = (f32x16)(0.0f);
  for (int ch = 0; ch < 4; ++ch) {
    f32x16 a4 = (f32x16)(0.0f);
    #pragma unroll
    for (int s = 0; s < 8; ++s) {
      frag32 af, bf;
      af.v = *(const u32x4*)(rdA + s * 1536);
      bf.v = *(const u32x4*)((const char*)Wm1t + (2 * s + hi) * 8192
                             + (ch * 128 + w * 32 + l31) * 16);
      a4 = __builtin_amdgcn_mfma_f32_32x32x16_bf16(bf.s, af.s, a4, 0, 0, 0);
    }
    __syncthreads();   // prior readers of r2 (xs / prev t3A) done
    #pragma unroll
    for (int jr = 0; jr < 4; ++jr) {
      const int c0 = w * 32 + jr * 8 + 4 * hi;
      const f32x4 bb = *(const f32x4*)(bm1 + ch * 128 + c0);
      const float v0 = gelu_tanh(a4[4 * jr + 0] + bb.x);
      const float v1 = gelu_tanh(a4[4 * jr + 1] + bb.y);
      const float v2 = gelu_tanh(a4[4 * jr + 2] + bb.z);
      const float v3 = gelu_tanh(a4[4 * jr + 3] + bb.w);
      u32x2 pk;
      pk.x = cvt_pk_bf16(v0, v1);
      pk.y = cvt_pk_bf16(v2, v3);
      *(u32x2*)(t3A + (c0 >> 4) * 1536 + l31 * 48 + ((c0 >> 3) & 1) * 16 + (c0 & 7) * 2) = pk;
    }
    __syncthreads();
    #pragma unroll
    for (int s = 0; s < 8; ++s) {
      frag32 af, bf;
      af.v = *(const u32x4*)(t3A + s * 1536 + l31 * 48 + hi * 16);
      bf.v = *(const u32x4*)((const char*)Wm2t + (ch * 16 + 2 * s + hi) * 2048
                             + (w * 32 + l31) * 16);
      acc5 = __builtin_amdgcn_mfma_f32_32x32x16_bf16(bf.s, af.s, acc5, 0, 0, 0);
    }
    __syncthreads();
  }

  // ---- epilogue: pre = x + acc5 + bm2 -> LN2 -> out ----
  #pragma unroll
  for (int q = 0; q < 16; ++q) {
    const int col = w * 32 + (q & 3) + 8 * (q >> 2) + 4 * hi;
    xs[l31 * XSTR + col] = acc5[q];
  }
  __syncthreads();
  #pragma unroll
  for (int it = 0; it < 4; ++it) {
    const int u = t + it * 256;
    const int row = u >> 5, c4 = (u & 31) * 4;
    f32x4 v = *(f32x4*)&xs[row * XSTR + c4];
    const u32x2 xx = *(const u32x2*)(xA + (c4 >> 4) * 1536 + row * 48
                                     + ((c4 >> 3) & 1) * 16 + (c4 & 7) * 2);
    const f32x4 b = *(const f32x4*)&bm2[c4];
    v.x += bf_lo(xx.x) + b.x;
    v.y += bf_hi(xx.x) + b.y;
    v.z += bf_lo(xx.y) + b.z;
    v.w += bf_hi(xx.y) + b.w;
    *(f32x4*)&xs[row * XSTR + c4] = v;
  }
  __syncthreads();
  ln_rows16(xs, XSTR, out + (size_t)m0 * 128, 128, ln2g, ln2b, t);
  ln_rows16(xs + 16 * XSTR, XSTR, out + (size_t)(m0 + 16) * 128, 128, ln2g, ln2b, t);
}

// ---------------------------------------------------------------------------
extern "C" void kernel_launch(void* const* d_in, const int* in_sizes, int n_in,
                              void* d_out, int out_size, void* d_ws, size_t ws_size,
                              hipStream_t stream)
{
  const float* src_exp = (const float*)d_in[0];
  const float* prot    = (const float*)d_in[1];
  const float* pvec    = (const float*)d_in[2];
  const int*   eidx0   = (const int*)d_in[3];
  const float* lig     = (const float*)d_in[4];
  const float* eattr   = (const float*)d_in[5];
  const int*   eidx1   = (const int*)d_in[6];
  const float* Watt0 = (const float*)d_in[7];
  const float* batt0 = (const float*)d_in[8];
  const float* a0    = (const float*)d_in[9];
  const float* Wval0 = (const float*)d_in[10];
  const float* bval0 = (const float*)d_in[11];
  const float* Watt1 = (const float*)d_in[12];
  const float* batt1 = (const float*)d_in[13];
  const float* a1    = (const float*)d_in[14];
  const float* Wval1 = (const float*)d_in[15];
  const float* bval1 = (const float*)d_in[16];
  const float* Wh1  = (const float*)d_in[17];
  const float* bh1  = (const float*)d_in[18];
  const float* Wh2  = (const float*)d_in[19];
  const float* bh2  = (const float*)d_in[20];
  const float* ln1g = (const float*)d_in[21];
  const float* ln1b = (const float*)d_in[22];
  const float* Wm1  = (const float*)d_in[23];
  const float* bm1  = (const float*)d_in[24];
  const float* Wm2  = (const float*)d_in[25];
  const float* bm2  = (const float*)d_in[26];
  const float* ln2g = (const float*)d_in[27];
  const float* ln2b = (const float*)d_in[28];

  char* w = (char*)d_ws;
  size_t o = 0;
  auto take = [&](size_t b) -> void* {
    void* p = w + o;
    o += (b + 255) & ~(size_t)255;
    return p;
  };
  int* cnt0 = (int*)take(8192 * 4);   // cnt0,cnt1,cur0,cur1 contiguous (zeroed in prep)
  int* cnt1 = (int*)take(8192 * 4);
  int* cur0 = (int*)take(8192 * 4);
  int* cur1 = (int*)take(8192 * 4);
  int* off0 = (int*)take(8193 * 4);
  int* off1 = (int*)take(8193 * 4);
  int* pel0 = (int*)take((size_t)E_PP * 4);
  int* pel1 = (int*)take((size_t)E_LP * 4);
  ushort_t* Bt0 = (ushort_t*)take((size_t)576 * 256 * 2);
  ushort_t* Bt1 = (ushort_t*)take((size_t)384 * 256 * 2);
  ushort_t* Wh1t = (ushort_t*)take((size_t)128 * 128 * 2);
  ushort_t* Wh2t = (ushort_t*)take((size_t)128 * 128 * 2);
  ushort_t* Wm1t = (ushort_t*)take((size_t)128 * 512 * 2);
  ushort_t* Wm2t = (ushort_t*)take((size_t)512 * 128 * 2);
  float* P = (float*)take(768 * 4);
  ushort_t* att = (ushort_t*)take((size_t)N_PROT * 128 * 2);
  char*  ev0 = (char*)take((size_t)E_PP * 256);
  char*  ev1 = (char*)take((size_t)E_LP * 256);
  float* eb0 = (float*)take((size_t)E_PP * 16);
  float* eb1 = (float*)take((size_t)E_LP * 16);

  prep_all<<<1731, 256, 0, stream>>>(Watt0, Wval0, Watt1, Wval1,
                                     Wh1, Wh2, Wm1, Wm2,
                                     batt0, a0, bval0, batt1, a1, bval1,
                                     Bt0, Bt1, Wh1t, Wh2t, Wm1t, Wm2t, P, cnt0);

  csr_hist<<<E_PP / 256, 256, 0, stream>>>(eidx0, eidx1, cnt0, cnt1);
  csr_scan2<<<2, 1024, 0, stream>>>(cnt0, off0, cnt1, off1);
  csr_scat<<<E_PP / 256, 256, 0, stream>>>(eidx0, eidx1, off0, off1,
                                           cur0, cur1, pel0, pel1);

  edge_gat14<<<NB0 + NB1, 256, 0, stream>>>(
      src_exp, prot, lig, eattr, eidx0, eidx1, pel0, pel1, Bt0, Bt1, P,
      ev0, eb0, ev1, eb1);

  seg_gather<<<N_PROT / 8, 256, 0, stream>>>(off0, ev0, eb0, off1, ev1, eb1, att);

  node_mfma<<<N_PROT / 32, 256, 0, stream>>>(
      att, prot,
      Wh1t, bh1, Wh2t, bh2, ln1g, ln1b,
      Wm1t, bm1, Wm2t, bm2, ln2g, ln2b, (float*)d_out);

  hipMemcpyAsync((float*)d_out + (size_t)N_PROT * 128, pvec,
                 (size_t)N_PROT * 12 * sizeof(float), hipMemcpyDeviceToDevice, stream);
}